// Round 15
// baseline (278.079 us; speedup 1.0000x reference)
//
#include <hip/hip_runtime.h>
#include <math.h>

#define NB 64              // batches per 1024-thread block (16 waves x 4)
#define NSLAB 64           // 128 k-rows / 2 per slab
#define UNI_F 16384        // 64 KB: scratch (16 waves x 1KB f) UNION 2x16KB slab dbuf

// R15 = R12 base with NB=64 / 1024-thread blocks (single structural change).
// Five scheduling levers nulled at ~203-216us (occupancy knob, MLP, counted
// vmcnt x2, barrier halving); best-ever was R11's 190us at 80% occupancy
// DESPITE 58MB spill -> wall time tracks resident waves. This gets the full
// 32-wave cap cleanly:
//  - 16 waves x 4 batches; staging per batch HALVED (one 16KB slab / 64
//    batches); per-CU rendezvous count halved (1024 blocks).
//  - LDS: 2x16KB dbuf (uni[0..8191]) UNION 16x1KB transpose scratch
//    (uni[0..16383]) + 8.4KB lists = 72.3KB -> 2 blocks/CU = 32 waves (cap).
//  - launch_bounds(1024,4): no VGPR straitjacket (R11 lesson); natural ~40.
//  - staging: wave wv covers floats [wv*256, wv*256+256) of the 4096-float
//    slab with ONE global_load_lds (linear dest).
//  - gather/masks/rotation/transpose/LU identical to R12 per wave.
// k-sum ascending -> bitwise-identical results.

typedef float f32x2 __attribute__((ext_vector_type(2)));
typedef float f32x4 __attribute__((ext_vector_type(4)));

#define GLD_LDS16(gp, lp) __builtin_amdgcn_global_load_lds( \
    (const __attribute__((address_space(1))) void*)(gp),    \
    (__attribute__((address_space(3))) void*)(lp), 16, 0, 0)

// acc (f32x2) += half of a b128 load, one packed add (IEEE-identical)
#define PKADD(acc, half) asm("v_pk_add_f32 %0, %0, %1" : "+v"(acc) : "v"(half))

// force a wave-uniform u64 into SGPRs (prove uniformity to the compiler)
__device__ __forceinline__ unsigned long long uniform_u64(unsigned long long x) {
    unsigned lo = __builtin_amdgcn_readfirstlane((unsigned)x);
    unsigned hi = __builtin_amdgcn_readfirstlane((unsigned)(x >> 32));
    return ((unsigned long long)hi << 32) | lo;
}

__global__ __launch_bounds__(1024, 4) void backflow_kernel(
    const int* __restrict__ nocc,   // (B,128) int32 0/1
    const float* __restrict__ W,    // (128,2048) f32 row-major
    float* __restrict__ out,        // planar: [B re][B im]
    int B)
{
    __shared__ __align__(16) float uni[UNI_F];   // slab dbuf / scratch union
    __shared__ int lists[NB][33];

    const int tid = threadIdx.x;

    // ---------------- phase 1: occupancy -> row lists (gather offsets) ------
    {
        const int bib1 = tid >> 4;                 // 0..63
        const int l16  = tid & 15;
        int batch1 = blockIdx.x * NB + bib1;
        if (batch1 >= B) batch1 = B - 1;
        const int4* np = reinterpret_cast<const int4*>(nocc + (size_t)batch1 * 128 + l16 * 8);
        int4 v0 = np[0];
        int4 v1 = np[1];
        unsigned nib = 0;
        nib |= (v0.x != 0) ? 1u   : 0u;
        nib |= (v0.y != 0) ? 2u   : 0u;
        nib |= (v0.z != 0) ? 4u   : 0u;
        nib |= (v0.w != 0) ? 8u   : 0u;
        nib |= (v1.x != 0) ? 16u  : 0u;
        nib |= (v1.y != 0) ? 32u  : 0u;
        nib |= (v1.z != 0) ? 64u  : 0u;
        nib |= (v1.w != 0) ? 128u : 0u;
        const int cnt = __popc(nib);
        int incl = cnt;
        const int seg = l16 & 7;
        #pragma unroll
        for (int d = 1; d < 8; d <<= 1) {
            int t = __shfl_up(incl, d, 8);
            if (seg >= d) incl += t;
        }
        int pos = ((l16 >> 3) << 4) + (incl - cnt);
        const int k0 = l16 * 8;
        #pragma unroll
        for (int b = 0; b < 8; b++) {
            if (nib & (1u << b)) lists[bib1][pos++] = k0 + b;
        }
    }
    __syncthreads();

    // ---------------- ids ----------------
    const int lane = tid & 63;
    const int wv   = __builtin_amdgcn_readfirstlane(tid >> 6);  // 0..15
    const int wb0  = wv << 2;            // first batch-in-wave (0..60)

    const int rowidx = lane >> 1;        // owned A-row 0..31
    const int h      = lane & 1;         // 8-float half of the 16-col row
    const int m2     = rowidx >> 4;      // spin of owned row
    const int rot    = rowidx & 1;       // chunk-parity rotation key

    // ---------------- per-wave occupancy masks -> SGPRs ----------------
    unsigned long long b0lo, b0hi, b1lo, b1hi, b2lo, b2hi, b3lo, b3hi;
    {
        const size_t base = (size_t)blockIdx.x * NB + wb0;
        int g0 = (int)base + 0, g1 = (int)base + 1, g2 = (int)base + 2, g3 = (int)base + 3;
        if (g0 >= B) g0 = B - 1;
        if (g1 >= B) g1 = B - 1;
        if (g2 >= B) g2 = B - 1;
        if (g3 >= B) g3 = B - 1;
        const int* p0 = nocc + (size_t)g0 * 128;
        const int* p1 = nocc + (size_t)g1 * 128;
        const int* p2 = nocc + (size_t)g2 * 128;
        const int* p3 = nocc + (size_t)g3 * 128;
        b0lo = uniform_u64(__ballot(p0[lane] != 0));
        b0hi = uniform_u64(__ballot(p0[64 + lane] != 0));
        b1lo = uniform_u64(__ballot(p1[lane] != 0));
        b1hi = uniform_u64(__ballot(p1[64 + lane] != 0));
        b2lo = uniform_u64(__ballot(p2[lane] != 0));
        b2hi = uniform_u64(__ballot(p2[64 + lane] != 0));
        b3lo = uniform_u64(__ballot(p3[lane] != 0));
        b3hi = uniform_u64(__ballot(p3[64 + lane] != 0));
    }

    // ---------------- staging setup (linear; 16 waves cover a 4096-f slab) --
    const int col_l = (wv << 8) + (lane << 2);       // 0..4095 floats
    const char* gp0 = (const char*)(W + col_l);
    char* const lb_off = (char*)uni + (wv << 10);    // byte offset of wave slice

    GLD_LDS16(gp0, lb_off);            // prologue: slab 0 -> buffer 0
    gp0 += 16384;

    // per-batch row offsets (bytes within one staged k-row)
    int off00, off01, off10, off11, off20, off21, off30, off31;
    {
        const int r0 = lists[wb0 + 0][rowidx] - (m2 << 6);
        const int r1 = lists[wb0 + 1][rowidx] - (m2 << 6);
        const int r2 = lists[wb0 + 2][rowidx] - (m2 << 6);
        const int r3 = lists[wb0 + 3][rowidx] - (m2 << 6);
        const int cbase = (m2 << 6) + (h << 5);
        off00 = (r0 << 7) + cbase + ((0 ^ rot) << 4);
        off01 = (r0 << 7) + cbase + ((1 ^ rot) << 4);
        off10 = (r1 << 7) + cbase + ((0 ^ rot) << 4);
        off11 = (r1 << 7) + cbase + ((1 ^ rot) << 4);
        off20 = (r2 << 7) + cbase + ((0 ^ rot) << 4);
        off21 = (r2 << 7) + cbase + ((1 ^ rot) << 4);
        off30 = (r3 << 7) + cbase + ((0 ^ rot) << 4);
        off31 = (r3 << 7) + cbase + ((1 ^ rot) << 4);
    }

    f32x2 acc[4][4] = {};   // [batch][2*slot+e]; slots 0,1 = chunk q=2h+rot,
                            //                    slots 2,3 = chunk q=2h+1-rot

    __syncthreads();   // slab 0 resident (compiler drains vmcnt)

    // ---------------- main loop: stage next, gather current ----------------
    #define GBODY(bb, oA, oB, kb)                                              \
        {                                                                      \
            const f32x4 v0 = *reinterpret_cast<const f32x4*>((kb) + (oA));     \
            const f32x4 v1 = *reinterpret_cast<const f32x4*>((kb) + (oB));     \
            PKADD(acc[bb][0], v0.lo); PKADD(acc[bb][1], v0.hi);                \
            PKADD(acc[bb][2], v1.lo); PKADD(acc[bb][3], v1.hi);                \
        }

    unsigned long long r0m = b0lo, r1m = b1lo, r2m = b2lo, r3m = b3lo;
    #pragma unroll 1
    for (int s = 0; s < NSLAB; s++) {
        if (s == 32) { r0m = b0hi; r1m = b1hi; r2m = b2hi; r3m = b3hi; }
        if (s < NSLAB - 1) {
            GLD_LDS16(gp0, (char*)uni + (((s + 1) & 1) << 14) + (wv << 10));
            gp0 += 16384;
        }
        const char* cpB = (const char*)uni + ((s & 1) << 14);
        if (r0m & 1ull) GBODY(0, off00, off01, cpB)
        if (r0m & 2ull) GBODY(0, off00, off01, cpB + 8192)
        if (r1m & 1ull) GBODY(1, off10, off11, cpB)
        if (r1m & 2ull) GBODY(1, off10, off11, cpB + 8192)
        if (r2m & 1ull) GBODY(2, off20, off21, cpB)
        if (r2m & 2ull) GBODY(2, off20, off21, cpB + 8192)
        if (r3m & 1ull) GBODY(3, off30, off31, cpB)
        if (r3m & 2ull) GBODY(3, off30, off31, cpB + 8192)
        r0m >>= 2; r1m >>= 2; r2m >>= 2; r3m >>= 2;
        __syncthreads();
    }
    // final barrier passed: all gathers done -> bufs dead, reuse as scratch

    // ---------------- within-wave transpose via exact-fit swizzled scratch --
    const int g   = lane >> 3;          // LU group 0..7
    const int s8  = lane & 7;
    const int m   = g & 1;              // 0 = up, 1 = dn
    const int bwl = g >> 1;             // batch-in-wave 0..3
    int batch = blockIdx.x * NB + wb0 + bwl;
    const bool valid = (batch < B);
    if (!valid) batch = B - 1;

    // scratch: per wave 1024 f = [2 batches][32 rows][16]; chunk q of row r
    // stored at physical chunk q ^ ((r>>1)&3).
    float* const sw = uni + (wv << 8) * 4;      // = uni + wv*1024 floats
    const int wsw = (rowidx >> 1) & 3;
    const int q0 = (h << 1) + rot;          // logical chunk in acc slots 0,1
    const int q1 = (h << 1) + (1 - rot);    // logical chunk in acc slots 2,3
    float* const wr0 = sw + rowidx * 16 + ((q0 ^ wsw) << 2);
    float* const wr1 = sw + rowidx * 16 + ((q1 ^ wsw) << 2);
    float a0[16], a1[16];

    // pass A: write batches 0,1; LU-read for lanes 0..31
    {
        f32x4 t;
        t.lo = acc[0][0]; t.hi = acc[0][1]; *reinterpret_cast<f32x4*>(wr0) = t;
        t.lo = acc[0][2]; t.hi = acc[0][3]; *reinterpret_cast<f32x4*>(wr1) = t;
        t.lo = acc[1][0]; t.hi = acc[1][1]; *reinterpret_cast<f32x4*>(wr0 + 512) = t;
        t.lo = acc[1][2]; t.hi = acc[1][3]; *reinterpret_cast<f32x4*>(wr1 + 512) = t;
    }
    asm volatile("s_waitcnt lgkmcnt(0)" ::: "memory");
    __builtin_amdgcn_sched_barrier(0);
    if (lane < 32) {
        const float* rbase = sw + bwl * 512;
        const int ra = (m << 4) + s8;
        const int rb = ra + 8;
        const int va = (ra >> 1) & 3;       // == (rb>>1)&3
        #pragma unroll
        for (int q = 0; q < 4; q++) {
            f32x4 u0 = *reinterpret_cast<const f32x4*>(rbase + ra * 16 + ((q ^ va) << 2));
            f32x4 u1 = *reinterpret_cast<const f32x4*>(rbase + rb * 16 + ((q ^ va) << 2));
            a0[q*4+0] = u0.x; a0[q*4+1] = u0.y; a0[q*4+2] = u0.z; a0[q*4+3] = u0.w;
            a1[q*4+0] = u1.x; a1[q*4+1] = u1.y; a1[q*4+2] = u1.z; a1[q*4+3] = u1.w;
        }
    }
    asm volatile("s_waitcnt lgkmcnt(0)" ::: "memory");
    __builtin_amdgcn_sched_barrier(0);
    // pass B: overwrite with batches 2,3; LU-read for lanes 32..63
    {
        f32x4 t;
        t.lo = acc[2][0]; t.hi = acc[2][1]; *reinterpret_cast<f32x4*>(wr0) = t;
        t.lo = acc[2][2]; t.hi = acc[2][3]; *reinterpret_cast<f32x4*>(wr1) = t;
        t.lo = acc[3][0]; t.hi = acc[3][1]; *reinterpret_cast<f32x4*>(wr0 + 512) = t;
        t.lo = acc[3][2]; t.hi = acc[3][3]; *reinterpret_cast<f32x4*>(wr1 + 512) = t;
    }
    asm volatile("s_waitcnt lgkmcnt(0)" ::: "memory");
    __builtin_amdgcn_sched_barrier(0);
    if (lane >= 32) {
        const float* rbase = sw + (bwl - 2) * 512;
        const int ra = (m << 4) + s8;
        const int rb = ra + 8;
        const int va = (ra >> 1) & 3;
        #pragma unroll
        for (int q = 0; q < 4; q++) {
            f32x4 u0 = *reinterpret_cast<const f32x4*>(rbase + ra * 16 + ((q ^ va) << 2));
            f32x4 u1 = *reinterpret_cast<const f32x4*>(rbase + rb * 16 + ((q ^ va) << 2));
            a0[q*4+0] = u0.x; a0[q*4+1] = u0.y; a0[q*4+2] = u0.z; a0[q*4+3] = u0.w;
            a1[q*4+0] = u1.x; a1[q*4+1] = u1.y; a1[q*4+2] = u1.z; a1[q*4+3] = u1.w;
        }
    }

    // ---------------- LU, implicit partial pivoting (register rows) --------
    unsigned active = 0xffffu;
    int inv = 0;
    float myd0 = 1.f, myd1 = 1.f;

    #pragma unroll
    for (int k = 0; k < 16; k++) {
        const unsigned act0 = (active >> s8) & 1u;
        const unsigned act1 = (active >> (s8 + 8)) & 1u;
        float av = act0 ? fabsf(a0[k]) : -1.f;
        int idx = s8;
        {
            float av1 = act1 ? fabsf(a1[k]) : -1.f;
            if (av1 > av) { av = av1; idx = s8 + 8; }
        }
        #pragma unroll
        for (int d = 1; d < 8; d <<= 1) {
            float ov = __shfl_xor(av, d, 8);
            int   oi = __shfl_xor(idx, d, 8);
            if (ov > av || (ov == av && oi < idx)) { av = ov; idx = oi; }
        }
        const int p = idx;
        const int plane = p & 7;
        const bool phi = (p & 8) != 0;
        float psel = phi ? a1[k] : a0[k];
        const float pk = __shfl(psel, plane, 8);
        const float rcp = 1.0f / pk;

        if (s8 == p)     myd0 = pk;
        if (s8 + 8 == p) myd1 = pk;
        inv += __popc(active & ((1u << p) - 1u));
        active &= ~(1u << p);

        const float f0 = (act0 && s8 != p)       ? a0[k] * rcp : 0.f;
        const float f1 = (act1 && (s8 + 8) != p) ? a1[k] * rcp : 0.f;

        #pragma unroll
        for (int j = k + 1; j < 16; j++) {
            float sel = phi ? a1[j] : a0[j];
            float pv = __shfl(sel, plane, 8);
            a0[j] = fmaf(-f0, pv, a0[j]);
            a1[j] = fmaf(-f1, pv, a1[j]);
        }
    }

    float ld = logf(fabsf(myd0)) + logf(fabsf(myd1));
    int ng = ((myd0 < 0.f) ? 1 : 0) + ((myd1 < 0.f) ? 1 : 0);
    #pragma unroll
    for (int d = 1; d < 8; d <<= 1) {
        ld += __shfl_xor(ld, d, 8);
        ng += __shfl_xor(ng, d, 8);
    }
    const int neg = (ng + inv) & 1;

    const float ld_o  = __shfl_xor(ld, 8, 16);
    const int   neg_o = __shfl_xor(neg, 8, 16);

    if ((lane & 15) == 0 && valid) {
        out[batch]     = ld + ld_o;                                      // re plane
        out[B + batch] = 3.14159265358979323846f * (float)(neg + neg_o); // im plane
    }
}

extern "C" void kernel_launch(void* const* d_in, const int* in_sizes, int n_in,
                              void* d_out, int out_size, void* d_ws, size_t ws_size,
                              hipStream_t stream) {
    const int* nocc = (const int*)d_in[0];
    const float* W  = (const float*)d_in[1];
    float* out = (float*)d_out;
    const int B = in_sizes[0] / 128;                 // 65536
    const int blocks = (B + NB - 1) / NB;            // 1024
    backflow_kernel<<<blocks, 1024, 0, stream>>>(nocc, W, out, B);
}

// Round 16
// 239.533 us; speedup vs baseline: 1.1609x; 1.1609x over previous
//
#include <hip/hip_runtime.h>
#include <math.h>

#define NB 32              // batches per 512-thread block
#define SLAB_F 4096        // slab = 2 W-rows x 2048 floats = 16 KB
#define NSLAB 64           // 128 k-rows / 2 per slab
#define UNI_F 8192         // 32 KB: slab dbuf UNION transpose scratch (exact fit)

// R16 = exact resubmission of R11, the session's fastest measured kernel
// (189-192us dispatch, 239.8us bench). Six scheduling levers on the
// spill-free base all nulled at ~203-216us (occupancy, MLP, counted-vmcnt
// x2, barrier halving, mega-blocks); R11's launch_bounds(512,8) variant
// (VGPR clamped to 32, ~58MB benign scratch traffic) remains ~7% faster
// than every spill-free sibling, outside the +-3% noise band. Mechanism
// unexplained (residency ruled out by R12's clean A/B); this run tests
// reproducibility of the win and locks in the empirical best.
//  - exact-fit transpose scratch [2 batches][32 rows][16], chunk swizzle
//    q ^ ((row>>1)&3) at write/read addresses (8 lanes/quad write).
//  - gather: full-wave, lane=(row,half); 2 full-activity ds_read_b128 per
//    occupied k; chunk-parity rotation c^rot (the 2KB/128B = 16cy floor;
//    8-way quad serialization PMC-counts as conflict - ignore).
//  - occupancy masks in SGPRs via ballot+readfirstlane (s_cbranch guards).
//  - 64x 2-row slabs, dbuf global_load_lds, __syncthreads drain.
//  - LU: 8-lane implicit partial pivot. k-sum ascending -> bitwise-identical.

typedef float f32x2 __attribute__((ext_vector_type(2)));
typedef float f32x4 __attribute__((ext_vector_type(4)));

#define GLD_LDS16(gp, lp) __builtin_amdgcn_global_load_lds( \
    (const __attribute__((address_space(1))) void*)(gp),    \
    (__attribute__((address_space(3))) void*)(lp), 16, 0, 0)

// acc (f32x2) += half of a b128 load, one packed add (IEEE-identical)
#define PKADD(acc, half) asm("v_pk_add_f32 %0, %0, %1" : "+v"(acc) : "v"(half))

// force a wave-uniform u64 into SGPRs (prove uniformity to the compiler)
__device__ __forceinline__ unsigned long long uniform_u64(unsigned long long x) {
    unsigned lo = __builtin_amdgcn_readfirstlane((unsigned)x);
    unsigned hi = __builtin_amdgcn_readfirstlane((unsigned)(x >> 32));
    return ((unsigned long long)hi << 32) | lo;
}

__global__ __launch_bounds__(512, 8) void backflow_kernel(
    const int* __restrict__ nocc,   // (B,128) int32 0/1
    const float* __restrict__ W,    // (128,2048) f32 row-major
    float* __restrict__ out,        // planar: [B re][B im]
    int B)
{
    __shared__ __align__(16) float uni[UNI_F];   // slab dbuf / scratch union
    __shared__ int lists[NB][33];

    const int tid = threadIdx.x;

    // ---------------- phase 1: occupancy -> row lists (gather offsets) ------
    {
        const int bib1 = tid >> 4;                 // 0..31
        const int l16  = tid & 15;
        int batch1 = blockIdx.x * NB + bib1;
        if (batch1 >= B) batch1 = B - 1;
        const int4* np = reinterpret_cast<const int4*>(nocc + (size_t)batch1 * 128 + l16 * 8);
        int4 v0 = np[0];
        int4 v1 = np[1];
        unsigned nib = 0;
        nib |= (v0.x != 0) ? 1u   : 0u;
        nib |= (v0.y != 0) ? 2u   : 0u;
        nib |= (v0.z != 0) ? 4u   : 0u;
        nib |= (v0.w != 0) ? 8u   : 0u;
        nib |= (v1.x != 0) ? 16u  : 0u;
        nib |= (v1.y != 0) ? 32u  : 0u;
        nib |= (v1.z != 0) ? 64u  : 0u;
        nib |= (v1.w != 0) ? 128u : 0u;
        const int cnt = __popc(nib);
        int incl = cnt;
        const int seg = l16 & 7;
        #pragma unroll
        for (int d = 1; d < 8; d <<= 1) {
            int t = __shfl_up(incl, d, 8);
            if (seg >= d) incl += t;
        }
        int pos = ((l16 >> 3) << 4) + (incl - cnt);
        const int k0 = l16 * 8;
        #pragma unroll
        for (int b = 0; b < 8; b++) {
            if (nib & (1u << b)) lists[bib1][pos++] = k0 + b;
        }
    }
    __syncthreads();

    // ---------------- ids ----------------
    const int lane = tid & 63;
    const int wv   = __builtin_amdgcn_readfirstlane(tid >> 6);  // 0..7
    const int wb0  = wv << 2;            // first batch-in-wave

    const int rowidx = lane >> 1;        // owned A-row 0..31
    const int h      = lane & 1;         // 8-float half of the 16-col row
    const int m2     = rowidx >> 4;      // spin of owned row
    const int rot    = rowidx & 1;       // chunk-parity rotation key

    // ---------------- per-wave occupancy masks -> SGPRs ----------------
    unsigned long long b0lo, b0hi, b1lo, b1hi, b2lo, b2hi, b3lo, b3hi;
    {
        const size_t base = (size_t)blockIdx.x * NB + wb0;
        int g0 = (int)base + 0, g1 = (int)base + 1, g2 = (int)base + 2, g3 = (int)base + 3;
        if (g0 >= B) g0 = B - 1;
        if (g1 >= B) g1 = B - 1;
        if (g2 >= B) g2 = B - 1;
        if (g3 >= B) g3 = B - 1;
        const int* p0 = nocc + (size_t)g0 * 128;
        const int* p1 = nocc + (size_t)g1 * 128;
        const int* p2 = nocc + (size_t)g2 * 128;
        const int* p3 = nocc + (size_t)g3 * 128;
        b0lo = uniform_u64(__ballot(p0[lane] != 0));
        b0hi = uniform_u64(__ballot(p0[64 + lane] != 0));
        b1lo = uniform_u64(__ballot(p1[lane] != 0));
        b1hi = uniform_u64(__ballot(p1[64 + lane] != 0));
        b2lo = uniform_u64(__ballot(p2[lane] != 0));
        b2hi = uniform_u64(__ballot(p2[64 + lane] != 0));
        b3lo = uniform_u64(__ballot(p3[lane] != 0));
        b3hi = uniform_u64(__ballot(p3[64 + lane] != 0));
    }

    // ---------------- staging setup (linear) ----------------
    const int col_l = (wv << 8) + (lane << 2);
    const char* gp0 = (const char*)(W + col_l);
    char* const lb_base = (char*)uni + (wv << 10);

    GLD_LDS16(gp0, lb_base);            // prologue: slab 0 -> buffer 0
    GLD_LDS16(gp0 + 8192, lb_base + 8192);
    gp0 += 16384;

    // per-batch row offsets (bytes within one staged k-row)
    int off00, off01, off10, off11, off20, off21, off30, off31;
    {
        const int r0 = lists[wb0 + 0][rowidx] - (m2 << 6);
        const int r1 = lists[wb0 + 1][rowidx] - (m2 << 6);
        const int r2 = lists[wb0 + 2][rowidx] - (m2 << 6);
        const int r3 = lists[wb0 + 3][rowidx] - (m2 << 6);
        const int cbase = (m2 << 6) + (h << 5);
        off00 = (r0 << 7) + cbase + ((0 ^ rot) << 4);
        off01 = (r0 << 7) + cbase + ((1 ^ rot) << 4);
        off10 = (r1 << 7) + cbase + ((0 ^ rot) << 4);
        off11 = (r1 << 7) + cbase + ((1 ^ rot) << 4);
        off20 = (r2 << 7) + cbase + ((0 ^ rot) << 4);
        off21 = (r2 << 7) + cbase + ((1 ^ rot) << 4);
        off30 = (r3 << 7) + cbase + ((0 ^ rot) << 4);
        off31 = (r3 << 7) + cbase + ((1 ^ rot) << 4);
    }

    f32x2 acc[4][4] = {};   // [batch][2*slot+e]; slots 0,1 = chunk q=2h+rot,
                            //                    slots 2,3 = chunk q=2h+1-rot

    __syncthreads();   // slab 0 resident (compiler drains vmcnt)

    // ---------------- main loop: stage next, gather current ----------------
    #define GBODY(bb, oA, oB, kb)                                              \
        {                                                                      \
            const f32x4 v0 = *reinterpret_cast<const f32x4*>((kb) + (oA));     \
            const f32x4 v1 = *reinterpret_cast<const f32x4*>((kb) + (oB));     \
            PKADD(acc[bb][0], v0.lo); PKADD(acc[bb][1], v0.hi);                \
            PKADD(acc[bb][2], v1.lo); PKADD(acc[bb][3], v1.hi);                \
        }

    unsigned long long r0m = b0lo, r1m = b1lo, r2m = b2lo, r3m = b3lo;
    #pragma unroll 1
    for (int s = 0; s < NSLAB; s++) {
        if (s == 32) { r0m = b0hi; r1m = b1hi; r2m = b2hi; r3m = b3hi; }
        if (s < NSLAB - 1) {
            char* lb = (char*)uni + (((s + 1) & 1) << 14) + (wv << 10);
            GLD_LDS16(gp0, lb);
            GLD_LDS16(gp0 + 8192, lb + 8192);
            gp0 += 16384;
        }
        const char* cpB = (const char*)uni + ((s & 1) << 14);
        if (r0m & 1ull) GBODY(0, off00, off01, cpB)
        if (r0m & 2ull) GBODY(0, off00, off01, cpB + 8192)
        if (r1m & 1ull) GBODY(1, off10, off11, cpB)
        if (r1m & 2ull) GBODY(1, off10, off11, cpB + 8192)
        if (r2m & 1ull) GBODY(2, off20, off21, cpB)
        if (r2m & 2ull) GBODY(2, off20, off21, cpB + 8192)
        if (r3m & 1ull) GBODY(3, off30, off31, cpB)
        if (r3m & 2ull) GBODY(3, off30, off31, cpB + 8192)
        r0m >>= 2; r1m >>= 2; r2m >>= 2; r3m >>= 2;
        __syncthreads();
    }
    // final barrier passed: all gathers done -> bufs dead, reuse as scratch

    // ---------------- within-wave transpose via exact-fit swizzled scratch --
    const int g   = lane >> 3;          // LU group 0..7
    const int s8  = lane & 7;
    const int m   = g & 1;              // 0 = up, 1 = dn
    const int bwl = g >> 1;             // batch-in-wave 0..3
    int batch = blockIdx.x * NB + wb0 + bwl;
    const bool valid = (batch < B);
    if (!valid) batch = B - 1;

    // scratch: per wave 1024 f = [2 batches][32 rows][16]; chunk q of row r
    // stored at physical chunk q ^ ((r>>1)&3).
    float* const sw = uni + (wv << 10);
    const int wsw = (rowidx >> 1) & 3;
    const int q0 = (h << 1) + rot;          // logical chunk in acc slots 0,1
    const int q1 = (h << 1) + (1 - rot);    // logical chunk in acc slots 2,3
    float* const wr0 = sw + rowidx * 16 + ((q0 ^ wsw) << 2);
    float* const wr1 = sw + rowidx * 16 + ((q1 ^ wsw) << 2);
    float a0[16], a1[16];

    // pass A: write batches 0,1; LU-read for lanes 0..31
    {
        f32x4 t;
        t.lo = acc[0][0]; t.hi = acc[0][1]; *reinterpret_cast<f32x4*>(wr0) = t;
        t.lo = acc[0][2]; t.hi = acc[0][3]; *reinterpret_cast<f32x4*>(wr1) = t;
        t.lo = acc[1][0]; t.hi = acc[1][1]; *reinterpret_cast<f32x4*>(wr0 + 512) = t;
        t.lo = acc[1][2]; t.hi = acc[1][3]; *reinterpret_cast<f32x4*>(wr1 + 512) = t;
    }
    asm volatile("s_waitcnt lgkmcnt(0)" ::: "memory");
    __builtin_amdgcn_sched_barrier(0);
    if (lane < 32) {
        const float* rbase = sw + bwl * 512;
        const int ra = (m << 4) + s8;
        const int rb = ra + 8;
        const int va = (ra >> 1) & 3;       // == (rb>>1)&3
        #pragma unroll
        for (int q = 0; q < 4; q++) {
            f32x4 u0 = *reinterpret_cast<const f32x4*>(rbase + ra * 16 + ((q ^ va) << 2));
            f32x4 u1 = *reinterpret_cast<const f32x4*>(rbase + rb * 16 + ((q ^ va) << 2));
            a0[q*4+0] = u0.x; a0[q*4+1] = u0.y; a0[q*4+2] = u0.z; a0[q*4+3] = u0.w;
            a1[q*4+0] = u1.x; a1[q*4+1] = u1.y; a1[q*4+2] = u1.z; a1[q*4+3] = u1.w;
        }
    }
    asm volatile("s_waitcnt lgkmcnt(0)" ::: "memory");
    __builtin_amdgcn_sched_barrier(0);
    // pass B: overwrite with batches 2,3; LU-read for lanes 32..63
    {
        f32x4 t;
        t.lo = acc[2][0]; t.hi = acc[2][1]; *reinterpret_cast<f32x4*>(wr0) = t;
        t.lo = acc[2][2]; t.hi = acc[2][3]; *reinterpret_cast<f32x4*>(wr1) = t;
        t.lo = acc[3][0]; t.hi = acc[3][1]; *reinterpret_cast<f32x4*>(wr0 + 512) = t;
        t.lo = acc[3][2]; t.hi = acc[3][3]; *reinterpret_cast<f32x4*>(wr1 + 512) = t;
    }
    asm volatile("s_waitcnt lgkmcnt(0)" ::: "memory");
    __builtin_amdgcn_sched_barrier(0);
    if (lane >= 32) {
        const float* rbase = sw + (bwl - 2) * 512;
        const int ra = (m << 4) + s8;
        const int rb = ra + 8;
        const int va = (ra >> 1) & 3;
        #pragma unroll
        for (int q = 0; q < 4; q++) {
            f32x4 u0 = *reinterpret_cast<const f32x4*>(rbase + ra * 16 + ((q ^ va) << 2));
            f32x4 u1 = *reinterpret_cast<const f32x4*>(rbase + rb * 16 + ((q ^ va) << 2));
            a0[q*4+0] = u0.x; a0[q*4+1] = u0.y; a0[q*4+2] = u0.z; a0[q*4+3] = u0.w;
            a1[q*4+0] = u1.x; a1[q*4+1] = u1.y; a1[q*4+2] = u1.z; a1[q*4+3] = u1.w;
        }
    }

    // ---------------- LU, implicit partial pivoting (register rows) --------
    unsigned active = 0xffffu;
    int inv = 0;
    float myd0 = 1.f, myd1 = 1.f;

    #pragma unroll
    for (int k = 0; k < 16; k++) {
        const unsigned act0 = (active >> s8) & 1u;
        const unsigned act1 = (active >> (s8 + 8)) & 1u;
        float av = act0 ? fabsf(a0[k]) : -1.f;
        int idx = s8;
        {
            float av1 = act1 ? fabsf(a1[k]) : -1.f;
            if (av1 > av) { av = av1; idx = s8 + 8; }
        }
        #pragma unroll
        for (int d = 1; d < 8; d <<= 1) {
            float ov = __shfl_xor(av, d, 8);
            int   oi = __shfl_xor(idx, d, 8);
            if (ov > av || (ov == av && oi < idx)) { av = ov; idx = oi; }
        }
        const int p = idx;
        const int plane = p & 7;
        const bool phi = (p & 8) != 0;
        float psel = phi ? a1[k] : a0[k];
        const float pk = __shfl(psel, plane, 8);
        const float rcp = 1.0f / pk;

        if (s8 == p)     myd0 = pk;
        if (s8 + 8 == p) myd1 = pk;
        inv += __popc(active & ((1u << p) - 1u));
        active &= ~(1u << p);

        const float f0 = (act0 && s8 != p)       ? a0[k] * rcp : 0.f;
        const float f1 = (act1 && (s8 + 8) != p) ? a1[k] * rcp : 0.f;

        #pragma unroll
        for (int j = k + 1; j < 16; j++) {
            float sel = phi ? a1[j] : a0[j];
            float pv = __shfl(sel, plane, 8);
            a0[j] = fmaf(-f0, pv, a0[j]);
            a1[j] = fmaf(-f1, pv, a1[j]);
        }
    }

    float ld = logf(fabsf(myd0)) + logf(fabsf(myd1));
    int ng = ((myd0 < 0.f) ? 1 : 0) + ((myd1 < 0.f) ? 1 : 0);
    #pragma unroll
    for (int d = 1; d < 8; d <<= 1) {
        ld += __shfl_xor(ld, d, 8);
        ng += __shfl_xor(ng, d, 8);
    }
    const int neg = (ng + inv) & 1;

    const float ld_o  = __shfl_xor(ld, 8, 16);
    const int   neg_o = __shfl_xor(neg, 8, 16);

    if ((lane & 15) == 0 && valid) {
        out[batch]     = ld + ld_o;                                      // re plane
        out[B + batch] = 3.14159265358979323846f * (float)(neg + neg_o); // im plane
    }
}

extern "C" void kernel_launch(void* const* d_in, const int* in_sizes, int n_in,
                              void* d_out, int out_size, void* d_ws, size_t ws_size,
                              hipStream_t stream) {
    const int* nocc = (const int*)d_in[0];
    const float* W  = (const float*)d_in[1];
    float* out = (float*)d_out;
    const int B = in_sizes[0] / 128;                 // 65536
    const int blocks = (B + NB - 1) / NB;            // 2048
    backflow_kernel<<<blocks, 512, 0, stream>>>(nocc, W, out, B);
}

// Round 18
// 239.215 us; speedup vs baseline: 1.1625x; 1.0013x over previous
//
#include <hip/hip_runtime.h>
#include <math.h>

#define NB 32              // batches per 512-thread block
#define SLAB_F 4096        // slab = 2 W-rows x 2048 floats = 16 KB
#define NSLAB 64           // 128 k-rows / 2 per slab
#define UNI_F 8192         // 32 KB: slab dbuf UNION transpose scratch (exact fit)

// R17b = R17 with the PKADD constraint typo fixed ("+v" input -> "v").
// R17 = R16 (reproduced session-best: launch_bounds(512,8), 190us dispatch /
// 239.5us bench) + 4-VGPR loop-live-set shave to shrink the spill. Under the
// (512,8) VGPR-32 clamp, ~14-18 regs spill (~10 dwords/iter/wave = 40MB
// WRITE + 17MB scratch-reload FETCH). The second-chunk offsets satisfy
// off*1 == off*0 ^ 16 exactly (chunk bit = byte-addr bit 4; all other terms
// >= bit 5; no carries), so they are synthesized per use with one volatile
// v_xor_b32 (can't be hoisted into a live register). Everything else
// byte-identical to R16:
//  - exact-fit transpose scratch [2 batches][32 rows][16], chunk swizzle
//    q ^ ((row>>1)&3) at write/read addresses.
//  - gather: full-wave, lane=(row,half); 2 full-activity ds_read_b128 per
//    occupied k; chunk-parity rotation (the 2KB/128B=16cy LDS floor).
//  - occupancy masks in SGPRs via ballot+readfirstlane (s_cbranch guards).
//  - 64x 2-row slabs, dbuf global_load_lds, __syncthreads drain.
//  - LU: 8-lane implicit partial pivot. k-sum ascending -> bitwise-identical.

typedef float f32x2 __attribute__((ext_vector_type(2)));
typedef float f32x4 __attribute__((ext_vector_type(4)));

#define GLD_LDS16(gp, lp) __builtin_amdgcn_global_load_lds( \
    (const __attribute__((address_space(1))) void*)(gp),    \
    (__attribute__((address_space(3))) void*)(lp), 16, 0, 0)

// acc (f32x2) += half of a b128 load, one packed add (IEEE-identical)
#define PKADD(acc, half) asm("v_pk_add_f32 %0, %0, %1" : "+v"(acc) : "v"(half))

// force a wave-uniform u64 into SGPRs (prove uniformity to the compiler)
__device__ __forceinline__ unsigned long long uniform_u64(unsigned long long x) {
    unsigned lo = __builtin_amdgcn_readfirstlane((unsigned)x);
    unsigned hi = __builtin_amdgcn_readfirstlane((unsigned)(x >> 32));
    return ((unsigned long long)hi << 32) | lo;
}

__global__ __launch_bounds__(512, 8) void backflow_kernel(
    const int* __restrict__ nocc,   // (B,128) int32 0/1
    const float* __restrict__ W,    // (128,2048) f32 row-major
    float* __restrict__ out,        // planar: [B re][B im]
    int B)
{
    __shared__ __align__(16) float uni[UNI_F];   // slab dbuf / scratch union
    __shared__ int lists[NB][33];

    const int tid = threadIdx.x;

    // ---------------- phase 1: occupancy -> row lists (gather offsets) ------
    {
        const int bib1 = tid >> 4;                 // 0..31
        const int l16  = tid & 15;
        int batch1 = blockIdx.x * NB + bib1;
        if (batch1 >= B) batch1 = B - 1;
        const int4* np = reinterpret_cast<const int4*>(nocc + (size_t)batch1 * 128 + l16 * 8);
        int4 v0 = np[0];
        int4 v1 = np[1];
        unsigned nib = 0;
        nib |= (v0.x != 0) ? 1u   : 0u;
        nib |= (v0.y != 0) ? 2u   : 0u;
        nib |= (v0.z != 0) ? 4u   : 0u;
        nib |= (v0.w != 0) ? 8u   : 0u;
        nib |= (v1.x != 0) ? 16u  : 0u;
        nib |= (v1.y != 0) ? 32u  : 0u;
        nib |= (v1.z != 0) ? 64u  : 0u;
        nib |= (v1.w != 0) ? 128u : 0u;
        const int cnt = __popc(nib);
        int incl = cnt;
        const int seg = l16 & 7;
        #pragma unroll
        for (int d = 1; d < 8; d <<= 1) {
            int t = __shfl_up(incl, d, 8);
            if (seg >= d) incl += t;
        }
        int pos = ((l16 >> 3) << 4) + (incl - cnt);
        const int k0 = l16 * 8;
        #pragma unroll
        for (int b = 0; b < 8; b++) {
            if (nib & (1u << b)) lists[bib1][pos++] = k0 + b;
        }
    }
    __syncthreads();

    // ---------------- ids ----------------
    const int lane = tid & 63;
    const int wv   = __builtin_amdgcn_readfirstlane(tid >> 6);  // 0..7
    const int wb0  = wv << 2;            // first batch-in-wave

    const int rowidx = lane >> 1;        // owned A-row 0..31
    const int h      = lane & 1;         // 8-float half of the 16-col row
    const int m2     = rowidx >> 4;      // spin of owned row
    const int rot    = rowidx & 1;       // chunk-parity rotation key

    // ---------------- per-wave occupancy masks -> SGPRs ----------------
    unsigned long long b0lo, b0hi, b1lo, b1hi, b2lo, b2hi, b3lo, b3hi;
    {
        const size_t base = (size_t)blockIdx.x * NB + wb0;
        int g0 = (int)base + 0, g1 = (int)base + 1, g2 = (int)base + 2, g3 = (int)base + 3;
        if (g0 >= B) g0 = B - 1;
        if (g1 >= B) g1 = B - 1;
        if (g2 >= B) g2 = B - 1;
        if (g3 >= B) g3 = B - 1;
        const int* p0 = nocc + (size_t)g0 * 128;
        const int* p1 = nocc + (size_t)g1 * 128;
        const int* p2 = nocc + (size_t)g2 * 128;
        const int* p3 = nocc + (size_t)g3 * 128;
        b0lo = uniform_u64(__ballot(p0[lane] != 0));
        b0hi = uniform_u64(__ballot(p0[64 + lane] != 0));
        b1lo = uniform_u64(__ballot(p1[lane] != 0));
        b1hi = uniform_u64(__ballot(p1[64 + lane] != 0));
        b2lo = uniform_u64(__ballot(p2[lane] != 0));
        b2hi = uniform_u64(__ballot(p2[64 + lane] != 0));
        b3lo = uniform_u64(__ballot(p3[lane] != 0));
        b3hi = uniform_u64(__ballot(p3[64 + lane] != 0));
    }

    // ---------------- staging setup (linear) ----------------
    const int col_l = (wv << 8) + (lane << 2);
    const char* gp0 = (const char*)(W + col_l);
    char* const lb_base = (char*)uni + (wv << 10);

    GLD_LDS16(gp0, lb_base);            // prologue: slab 0 -> buffer 0
    GLD_LDS16(gp0 + 8192, lb_base + 8192);
    gp0 += 16384;

    // per-batch FIRST-chunk offsets (bytes within one staged k-row);
    // second chunk = first ^ 16 (bit-4 flip, no carries), synthesized per use.
    int off0, off1, off2, off3;
    {
        const int cbase = (m2 << 6) + (h << 5) + (rot << 4);
        off0 = ((lists[wb0 + 0][rowidx] - (m2 << 6)) << 7) + cbase;
        off1 = ((lists[wb0 + 1][rowidx] - (m2 << 6)) << 7) + cbase;
        off2 = ((lists[wb0 + 2][rowidx] - (m2 << 6)) << 7) + cbase;
        off3 = ((lists[wb0 + 3][rowidx] - (m2 << 6)) << 7) + cbase;
    }

    f32x2 acc[4][4] = {};   // [batch][2*slot+e]; slots 0,1 = chunk q=2h+rot,
                            //                    slots 2,3 = chunk q=2h+1-rot

    __syncthreads();   // slab 0 resident (compiler drains vmcnt)

    // ---------------- main loop: stage next, gather current ----------------
    // o2_ = oA ^ 16 via volatile v_xor: not hoistable -> no live register.
    #define GBODY(bb, oA, kb)                                                  \
        {                                                                      \
            int o2_;                                                           \
            asm volatile("v_xor_b32 %0, 16, %1" : "=v"(o2_) : "v"(oA));        \
            const f32x4 v0 = *reinterpret_cast<const f32x4*>((kb) + (oA));     \
            const f32x4 v1 = *reinterpret_cast<const f32x4*>((kb) + o2_);      \
            PKADD(acc[bb][0], v0.lo); PKADD(acc[bb][1], v0.hi);                \
            PKADD(acc[bb][2], v1.lo); PKADD(acc[bb][3], v1.hi);                \
        }

    unsigned long long r0m = b0lo, r1m = b1lo, r2m = b2lo, r3m = b3lo;
    #pragma unroll 1
    for (int s = 0; s < NSLAB; s++) {
        if (s == 32) { r0m = b0hi; r1m = b1hi; r2m = b2hi; r3m = b3hi; }
        if (s < NSLAB - 1) {
            char* lb = (char*)uni + (((s + 1) & 1) << 14) + (wv << 10);
            GLD_LDS16(gp0, lb);
            GLD_LDS16(gp0 + 8192, lb + 8192);
            gp0 += 16384;
        }
        const char* cpB = (const char*)uni + ((s & 1) << 14);
        if (r0m & 1ull) GBODY(0, off0, cpB)
        if (r0m & 2ull) GBODY(0, off0, cpB + 8192)
        if (r1m & 1ull) GBODY(1, off1, cpB)
        if (r1m & 2ull) GBODY(1, off1, cpB + 8192)
        if (r2m & 1ull) GBODY(2, off2, cpB)
        if (r2m & 2ull) GBODY(2, off2, cpB + 8192)
        if (r3m & 1ull) GBODY(3, off3, cpB)
        if (r3m & 2ull) GBODY(3, off3, cpB + 8192)
        r0m >>= 2; r1m >>= 2; r2m >>= 2; r3m >>= 2;
        __syncthreads();
    }
    // final barrier passed: all gathers done -> bufs dead, reuse as scratch

    // ---------------- within-wave transpose via exact-fit swizzled scratch --
    const int g   = lane >> 3;          // LU group 0..7
    const int s8  = lane & 7;
    const int m   = g & 1;              // 0 = up, 1 = dn
    const int bwl = g >> 1;             // batch-in-wave 0..3
    int batch = blockIdx.x * NB + wb0 + bwl;
    const bool valid = (batch < B);
    if (!valid) batch = B - 1;

    // scratch: per wave 1024 f = [2 batches][32 rows][16]; chunk q of row r
    // stored at physical chunk q ^ ((r>>1)&3).
    float* const sw = uni + (wv << 10);
    const int wsw = (rowidx >> 1) & 3;
    const int q0 = (h << 1) + rot;          // logical chunk in acc slots 0,1
    const int q1 = (h << 1) + (1 - rot);    // logical chunk in acc slots 2,3
    float* const wr0 = sw + rowidx * 16 + ((q0 ^ wsw) << 2);
    float* const wr1 = sw + rowidx * 16 + ((q1 ^ wsw) << 2);
    float a0[16], a1[16];

    // pass A: write batches 0,1; LU-read for lanes 0..31
    {
        f32x4 t;
        t.lo = acc[0][0]; t.hi = acc[0][1]; *reinterpret_cast<f32x4*>(wr0) = t;
        t.lo = acc[0][2]; t.hi = acc[0][3]; *reinterpret_cast<f32x4*>(wr1) = t;
        t.lo = acc[1][0]; t.hi = acc[1][1]; *reinterpret_cast<f32x4*>(wr0 + 512) = t;
        t.lo = acc[1][2]; t.hi = acc[1][3]; *reinterpret_cast<f32x4*>(wr1 + 512) = t;
    }
    asm volatile("s_waitcnt lgkmcnt(0)" ::: "memory");
    __builtin_amdgcn_sched_barrier(0);
    if (lane < 32) {
        const float* rbase = sw + bwl * 512;
        const int ra = (m << 4) + s8;
        const int rb = ra + 8;
        const int va = (ra >> 1) & 3;       // == (rb>>1)&3
        #pragma unroll
        for (int q = 0; q < 4; q++) {
            f32x4 u0 = *reinterpret_cast<const f32x4*>(rbase + ra * 16 + ((q ^ va) << 2));
            f32x4 u1 = *reinterpret_cast<const f32x4*>(rbase + rb * 16 + ((q ^ va) << 2));
            a0[q*4+0] = u0.x; a0[q*4+1] = u0.y; a0[q*4+2] = u0.z; a0[q*4+3] = u0.w;
            a1[q*4+0] = u1.x; a1[q*4+1] = u1.y; a1[q*4+2] = u1.z; a1[q*4+3] = u1.w;
        }
    }
    asm volatile("s_waitcnt lgkmcnt(0)" ::: "memory");
    __builtin_amdgcn_sched_barrier(0);
    // pass B: overwrite with batches 2,3; LU-read for lanes 32..63
    {
        f32x4 t;
        t.lo = acc[2][0]; t.hi = acc[2][1]; *reinterpret_cast<f32x4*>(wr0) = t;
        t.lo = acc[2][2]; t.hi = acc[2][3]; *reinterpret_cast<f32x4*>(wr1) = t;
        t.lo = acc[3][0]; t.hi = acc[3][1]; *reinterpret_cast<f32x4*>(wr0 + 512) = t;
        t.lo = acc[3][2]; t.hi = acc[3][3]; *reinterpret_cast<f32x4*>(wr1 + 512) = t;
    }
    asm volatile("s_waitcnt lgkmcnt(0)" ::: "memory");
    __builtin_amdgcn_sched_barrier(0);
    if (lane >= 32) {
        const float* rbase = sw + (bwl - 2) * 512;
        const int ra = (m << 4) + s8;
        const int rb = ra + 8;
        const int va = (ra >> 1) & 3;
        #pragma unroll
        for (int q = 0; q < 4; q++) {
            f32x4 u0 = *reinterpret_cast<const f32x4*>(rbase + ra * 16 + ((q ^ va) << 2));
            f32x4 u1 = *reinterpret_cast<const f32x4*>(rbase + rb * 16 + ((q ^ va) << 2));
            a0[q*4+0] = u0.x; a0[q*4+1] = u0.y; a0[q*4+2] = u0.z; a0[q*4+3] = u0.w;
            a1[q*4+0] = u1.x; a1[q*4+1] = u1.y; a1[q*4+2] = u1.z; a1[q*4+3] = u1.w;
        }
    }

    // ---------------- LU, implicit partial pivoting (register rows) --------
    unsigned active = 0xffffu;
    int inv = 0;
    float myd0 = 1.f, myd1 = 1.f;

    #pragma unroll
    for (int k = 0; k < 16; k++) {
        const unsigned act0 = (active >> s8) & 1u;
        const unsigned act1 = (active >> (s8 + 8)) & 1u;
        float av = act0 ? fabsf(a0[k]) : -1.f;
        int idx = s8;
        {
            float av1 = act1 ? fabsf(a1[k]) : -1.f;
            if (av1 > av) { av = av1; idx = s8 + 8; }
        }
        #pragma unroll
        for (int d = 1; d < 8; d <<= 1) {
            float ov = __shfl_xor(av, d, 8);
            int   oi = __shfl_xor(idx, d, 8);
            if (ov > av || (ov == av && oi < idx)) { av = ov; idx = oi; }
        }
        const int p = idx;
        const int plane = p & 7;
        const bool phi = (p & 8) != 0;
        float psel = phi ? a1[k] : a0[k];
        const float pk = __shfl(psel, plane, 8);
        const float rcp = 1.0f / pk;

        if (s8 == p)     myd0 = pk;
        if (s8 + 8 == p) myd1 = pk;
        inv += __popc(active & ((1u << p) - 1u));
        active &= ~(1u << p);

        const float f0 = (act0 && s8 != p)       ? a0[k] * rcp : 0.f;
        const float f1 = (act1 && (s8 + 8) != p) ? a1[k] * rcp : 0.f;

        #pragma unroll
        for (int j = k + 1; j < 16; j++) {
            float sel = phi ? a1[j] : a0[j];
            float pv = __shfl(sel, plane, 8);
            a0[j] = fmaf(-f0, pv, a0[j]);
            a1[j] = fmaf(-f1, pv, a1[j]);
        }
    }

    float ld = logf(fabsf(myd0)) + logf(fabsf(myd1));
    int ng = ((myd0 < 0.f) ? 1 : 0) + ((myd1 < 0.f) ? 1 : 0);
    #pragma unroll
    for (int d = 1; d < 8; d <<= 1) {
        ld += __shfl_xor(ld, d, 8);
        ng += __shfl_xor(ng, d, 8);
    }
    const int neg = (ng + inv) & 1;

    const float ld_o  = __shfl_xor(ld, 8, 16);
    const int   neg_o = __shfl_xor(neg, 8, 16);

    if ((lane & 15) == 0 && valid) {
        out[batch]     = ld + ld_o;                                      // re plane
        out[B + batch] = 3.14159265358979323846f * (float)(neg + neg_o); // im plane
    }
}

extern "C" void kernel_launch(void* const* d_in, const int* in_sizes, int n_in,
                              void* d_out, int out_size, void* d_ws, size_t ws_size,
                              hipStream_t stream) {
    const int* nocc = (const int*)d_in[0];
    const float* W  = (const float*)d_in[1];
    float* out = (float*)d_out;
    const int B = in_sizes[0] / 128;                 // 65536
    const int blocks = (B + NB - 1) / NB;            // 2048
    backflow_kernel<<<blocks, 512, 0, stream>>>(nocc, W, out, B);
}

// Round 19
// 237.110 us; speedup vs baseline: 1.1728x; 1.0089x over previous
//
#include <hip/hip_runtime.h>
#include <math.h>

#define NB 32              // batches per 512-thread block
#define SLAB_F 4096        // slab = 2 W-rows x 2048 floats = 16 KB
#define NSLAB 64           // 128 k-rows / 2 per slab
#define UNI_F 8192         // 32 KB: slab dbuf UNION transpose scratch (exact fit)

// R19 = R18 champion (launch_bounds(512,8), 190us dispatch / 239.2us bench)
// + s-loop unrolled by 2 so buffer parity is COMPILE-TIME: all four gather
// bases ({buf0,buf1}x{row0,row1} = 0/8192/16384/24576) and both staging
// bases become ds-instruction offset IMMEDIATES (offset:IMM, all <32768).
// The cpB/lb pointer registers and their per-iter (s&1) arithmetic leave
// the loop live set -> targets the VGPR-32 spill-reload path (R17's
// offset-shave failed its WRITE_SIZE tell; pointers are the next-cheapest
// spilled temps). Math, k-order, barrier placement byte-identical:
// per sub-iter: stage(s+1) -> gather(s) -> barrier; mask swap at s=32
// (u=16 top); epilogue s=62 (stage 63) + s=63 (no stage).
//  - exact-fit transpose scratch [2 batches][32 rows][16], chunk swizzle
//    q ^ ((row>>1)&3) at write/read addresses.
//  - gather: full-wave, lane=(row,half); 2 full-activity ds_read_b128 per
//    occupied k; chunk-parity rotation (the 2KB/128B=16cy LDS floor).
//  - occupancy masks in SGPRs via ballot+readfirstlane (s_cbranch guards).
//  - LU: 8-lane implicit partial pivot. k-sum ascending -> bitwise-identical.

typedef float f32x2 __attribute__((ext_vector_type(2)));
typedef float f32x4 __attribute__((ext_vector_type(4)));

#define GLD_LDS16(gp, lp) __builtin_amdgcn_global_load_lds( \
    (const __attribute__((address_space(1))) void*)(gp),    \
    (__attribute__((address_space(3))) void*)(lp), 16, 0, 0)

// acc (f32x2) += half of a b128 load, one packed add (IEEE-identical)
#define PKADD(acc, half) asm("v_pk_add_f32 %0, %0, %1" : "+v"(acc) : "v"(half))

// force a wave-uniform u64 into SGPRs (prove uniformity to the compiler)
__device__ __forceinline__ unsigned long long uniform_u64(unsigned long long x) {
    unsigned lo = __builtin_amdgcn_readfirstlane((unsigned)x);
    unsigned hi = __builtin_amdgcn_readfirstlane((unsigned)(x >> 32));
    return ((unsigned long long)hi << 32) | lo;
}

__global__ __launch_bounds__(512, 8) void backflow_kernel(
    const int* __restrict__ nocc,   // (B,128) int32 0/1
    const float* __restrict__ W,    // (128,2048) f32 row-major
    float* __restrict__ out,        // planar: [B re][B im]
    int B)
{
    __shared__ __align__(16) float uni[UNI_F];   // slab dbuf / scratch union
    __shared__ int lists[NB][33];

    const int tid = threadIdx.x;

    // ---------------- phase 1: occupancy -> row lists (gather offsets) ------
    {
        const int bib1 = tid >> 4;                 // 0..31
        const int l16  = tid & 15;
        int batch1 = blockIdx.x * NB + bib1;
        if (batch1 >= B) batch1 = B - 1;
        const int4* np = reinterpret_cast<const int4*>(nocc + (size_t)batch1 * 128 + l16 * 8);
        int4 v0 = np[0];
        int4 v1 = np[1];
        unsigned nib = 0;
        nib |= (v0.x != 0) ? 1u   : 0u;
        nib |= (v0.y != 0) ? 2u   : 0u;
        nib |= (v0.z != 0) ? 4u   : 0u;
        nib |= (v0.w != 0) ? 8u   : 0u;
        nib |= (v1.x != 0) ? 16u  : 0u;
        nib |= (v1.y != 0) ? 32u  : 0u;
        nib |= (v1.z != 0) ? 64u  : 0u;
        nib |= (v1.w != 0) ? 128u : 0u;
        const int cnt = __popc(nib);
        int incl = cnt;
        const int seg = l16 & 7;
        #pragma unroll
        for (int d = 1; d < 8; d <<= 1) {
            int t = __shfl_up(incl, d, 8);
            if (seg >= d) incl += t;
        }
        int pos = ((l16 >> 3) << 4) + (incl - cnt);
        const int k0 = l16 * 8;
        #pragma unroll
        for (int b = 0; b < 8; b++) {
            if (nib & (1u << b)) lists[bib1][pos++] = k0 + b;
        }
    }
    __syncthreads();

    // ---------------- ids ----------------
    const int lane = tid & 63;
    const int wv   = __builtin_amdgcn_readfirstlane(tid >> 6);  // 0..7
    const int wb0  = wv << 2;            // first batch-in-wave

    const int rowidx = lane >> 1;        // owned A-row 0..31
    const int h      = lane & 1;         // 8-float half of the 16-col row
    const int m2     = rowidx >> 4;      // spin of owned row
    const int rot    = rowidx & 1;       // chunk-parity rotation key

    // ---------------- per-wave occupancy masks -> SGPRs ----------------
    unsigned long long b0lo, b0hi, b1lo, b1hi, b2lo, b2hi, b3lo, b3hi;
    {
        const size_t base = (size_t)blockIdx.x * NB + wb0;
        int g0 = (int)base + 0, g1 = (int)base + 1, g2 = (int)base + 2, g3 = (int)base + 3;
        if (g0 >= B) g0 = B - 1;
        if (g1 >= B) g1 = B - 1;
        if (g2 >= B) g2 = B - 1;
        if (g3 >= B) g3 = B - 1;
        const int* p0 = nocc + (size_t)g0 * 128;
        const int* p1 = nocc + (size_t)g1 * 128;
        const int* p2 = nocc + (size_t)g2 * 128;
        const int* p3 = nocc + (size_t)g3 * 128;
        b0lo = uniform_u64(__ballot(p0[lane] != 0));
        b0hi = uniform_u64(__ballot(p0[64 + lane] != 0));
        b1lo = uniform_u64(__ballot(p1[lane] != 0));
        b1hi = uniform_u64(__ballot(p1[64 + lane] != 0));
        b2lo = uniform_u64(__ballot(p2[lane] != 0));
        b2hi = uniform_u64(__ballot(p2[64 + lane] != 0));
        b3lo = uniform_u64(__ballot(p3[lane] != 0));
        b3hi = uniform_u64(__ballot(p3[64 + lane] != 0));
    }

    // ---------------- staging setup (linear) ----------------
    const int col_l = (wv << 8) + (lane << 2);
    const char* gp0 = (const char*)(W + col_l);

    GLD_LDS16(gp0, (char*)uni + (wv << 10));            // slab 0 -> buffer 0
    GLD_LDS16(gp0 + 8192, (char*)uni + 8192 + (wv << 10));
    gp0 += 16384;

    // per-batch row offsets (bytes within one staged k-row)
    int off00, off01, off10, off11, off20, off21, off30, off31;
    {
        const int r0 = lists[wb0 + 0][rowidx] - (m2 << 6);
        const int r1 = lists[wb0 + 1][rowidx] - (m2 << 6);
        const int r2 = lists[wb0 + 2][rowidx] - (m2 << 6);
        const int r3 = lists[wb0 + 3][rowidx] - (m2 << 6);
        const int cbase = (m2 << 6) + (h << 5);
        off00 = (r0 << 7) + cbase + ((0 ^ rot) << 4);
        off01 = (r0 << 7) + cbase + ((1 ^ rot) << 4);
        off10 = (r1 << 7) + cbase + ((0 ^ rot) << 4);
        off11 = (r1 << 7) + cbase + ((1 ^ rot) << 4);
        off20 = (r2 << 7) + cbase + ((0 ^ rot) << 4);
        off21 = (r2 << 7) + cbase + ((1 ^ rot) << 4);
        off30 = (r3 << 7) + cbase + ((0 ^ rot) << 4);
        off31 = (r3 << 7) + cbase + ((1 ^ rot) << 4);
    }

    f32x2 acc[4][4] = {};   // [batch][2*slot+e]; slots 0,1 = chunk q=2h+rot,
                            //                    slots 2,3 = chunk q=2h+1-rot

    __syncthreads();   // slab 0 resident (compiler drains vmcnt)

    // ---------------- main loop: unroll-2, compile-time buffer parity -------
    #define GBODY(bb, oA, oB, BASE)                                            \
        {                                                                      \
            const f32x4 v0 = *reinterpret_cast<const f32x4*>(                  \
                (const char*)uni + (BASE) + (oA));                             \
            const f32x4 v1 = *reinterpret_cast<const f32x4*>(                  \
                (const char*)uni + (BASE) + (oB));                             \
            PKADD(acc[bb][0], v0.lo); PKADD(acc[bb][1], v0.hi);                \
            PKADD(acc[bb][2], v1.lo); PKADD(acc[bb][3], v1.hi);                \
        }

    // gather one slab (2 k-rows) from buffer at BASE, consume 2 mask bits
    #define GATHER_SLAB(BASE)                                                  \
        if (r0m & 1ull) GBODY(0, off00, off01, (BASE))                         \
        if (r0m & 2ull) GBODY(0, off00, off01, (BASE) + 8192)                  \
        if (r1m & 1ull) GBODY(1, off10, off11, (BASE))                         \
        if (r1m & 2ull) GBODY(1, off10, off11, (BASE) + 8192)                  \
        if (r2m & 1ull) GBODY(2, off20, off21, (BASE))                         \
        if (r2m & 2ull) GBODY(2, off20, off21, (BASE) + 8192)                  \
        if (r3m & 1ull) GBODY(3, off30, off31, (BASE))                         \
        if (r3m & 2ull) GBODY(3, off30, off31, (BASE) + 8192)                  \
        r0m >>= 2; r1m >>= 2; r2m >>= 2; r3m >>= 2;

    // stage next slab (2 k-rows) into buffer at BASE
    #define STAGE_SLAB(BASE)                                                   \
        {                                                                      \
            GLD_LDS16(gp0, (char*)uni + (BASE) + (wv << 10));                  \
            GLD_LDS16(gp0 + 8192, (char*)uni + (BASE) + 8192 + (wv << 10));   \
            gp0 += 16384;                                                      \
        }

    unsigned long long r0m = b0lo, r1m = b1lo, r2m = b2lo, r3m = b3lo;
    #pragma unroll 1
    for (int u = 0; u < 31; u++) {       // s = 2u (buf0) and 2u+1 (buf1)
        if (u == 16) { r0m = b0hi; r1m = b1hi; r2m = b2hi; r3m = b3hi; }
        // s = 2u: stage slab 2u+1 -> buf1; gather from buf0
        STAGE_SLAB(16384)
        GATHER_SLAB(0)
        __syncthreads();
        // s = 2u+1: stage slab 2u+2 -> buf0; gather from buf1
        STAGE_SLAB(0)
        GATHER_SLAB(16384)
        __syncthreads();
    }
    // epilogue: s = 62 (stage slab 63 -> buf1; gather buf0)
    {
        GLD_LDS16(gp0, (char*)uni + 16384 + (wv << 10));
        GLD_LDS16(gp0 + 8192, (char*)uni + 16384 + 8192 + (wv << 10));
    }
    GATHER_SLAB(0)
    __syncthreads();
    // s = 63 (no stage; gather buf1)
    GATHER_SLAB(16384)
    __syncthreads();   // all gathers done -> bufs dead, reuse as scratch

    // ---------------- within-wave transpose via exact-fit swizzled scratch --
    const int g   = lane >> 3;          // LU group 0..7
    const int s8  = lane & 7;
    const int m   = g & 1;              // 0 = up, 1 = dn
    const int bwl = g >> 1;             // batch-in-wave 0..3
    int batch = blockIdx.x * NB + wb0 + bwl;
    const bool valid = (batch < B);
    if (!valid) batch = B - 1;

    // scratch: per wave 1024 f = [2 batches][32 rows][16]; chunk q of row r
    // stored at physical chunk q ^ ((r>>1)&3).
    float* const sw = uni + (wv << 10);
    const int wsw = (rowidx >> 1) & 3;
    const int q0 = (h << 1) + rot;          // logical chunk in acc slots 0,1
    const int q1 = (h << 1) + (1 - rot);    // logical chunk in acc slots 2,3
    float* const wr0 = sw + rowidx * 16 + ((q0 ^ wsw) << 2);
    float* const wr1 = sw + rowidx * 16 + ((q1 ^ wsw) << 2);
    float a0[16], a1[16];

    // pass A: write batches 0,1; LU-read for lanes 0..31
    {
        f32x4 t;
        t.lo = acc[0][0]; t.hi = acc[0][1]; *reinterpret_cast<f32x4*>(wr0) = t;
        t.lo = acc[0][2]; t.hi = acc[0][3]; *reinterpret_cast<f32x4*>(wr1) = t;
        t.lo = acc[1][0]; t.hi = acc[1][1]; *reinterpret_cast<f32x4*>(wr0 + 512) = t;
        t.lo = acc[1][2]; t.hi = acc[1][3]; *reinterpret_cast<f32x4*>(wr1 + 512) = t;
    }
    asm volatile("s_waitcnt lgkmcnt(0)" ::: "memory");
    __builtin_amdgcn_sched_barrier(0);
    if (lane < 32) {
        const float* rbase = sw + bwl * 512;
        const int ra = (m << 4) + s8;
        const int rb = ra + 8;
        const int va = (ra >> 1) & 3;       // == (rb>>1)&3
        #pragma unroll
        for (int q = 0; q < 4; q++) {
            f32x4 u0 = *reinterpret_cast<const f32x4*>(rbase + ra * 16 + ((q ^ va) << 2));
            f32x4 u1 = *reinterpret_cast<const f32x4*>(rbase + rb * 16 + ((q ^ va) << 2));
            a0[q*4+0] = u0.x; a0[q*4+1] = u0.y; a0[q*4+2] = u0.z; a0[q*4+3] = u0.w;
            a1[q*4+0] = u1.x; a1[q*4+1] = u1.y; a1[q*4+2] = u1.z; a1[q*4+3] = u1.w;
        }
    }
    asm volatile("s_waitcnt lgkmcnt(0)" ::: "memory");
    __builtin_amdgcn_sched_barrier(0);
    // pass B: overwrite with batches 2,3; LU-read for lanes 32..63
    {
        f32x4 t;
        t.lo = acc[2][0]; t.hi = acc[2][1]; *reinterpret_cast<f32x4*>(wr0) = t;
        t.lo = acc[2][2]; t.hi = acc[2][3]; *reinterpret_cast<f32x4*>(wr1) = t;
        t.lo = acc[3][0]; t.hi = acc[3][1]; *reinterpret_cast<f32x4*>(wr0 + 512) = t;
        t.lo = acc[3][2]; t.hi = acc[3][3]; *reinterpret_cast<f32x4*>(wr1 + 512) = t;
    }
    asm volatile("s_waitcnt lgkmcnt(0)" ::: "memory");
    __builtin_amdgcn_sched_barrier(0);
    if (lane >= 32) {
        const float* rbase = sw + (bwl - 2) * 512;
        const int ra = (m << 4) + s8;
        const int rb = ra + 8;
        const int va = (ra >> 1) & 3;
        #pragma unroll
        for (int q = 0; q < 4; q++) {
            f32x4 u0 = *reinterpret_cast<const f32x4*>(rbase + ra * 16 + ((q ^ va) << 2));
            f32x4 u1 = *reinterpret_cast<const f32x4*>(rbase + rb * 16 + ((q ^ va) << 2));
            a0[q*4+0] = u0.x; a0[q*4+1] = u0.y; a0[q*4+2] = u0.z; a0[q*4+3] = u0.w;
            a1[q*4+0] = u1.x; a1[q*4+1] = u1.y; a1[q*4+2] = u1.z; a1[q*4+3] = u1.w;
        }
    }

    // ---------------- LU, implicit partial pivoting (register rows) --------
    unsigned active = 0xffffu;
    int inv = 0;
    float myd0 = 1.f, myd1 = 1.f;

    #pragma unroll
    for (int k = 0; k < 16; k++) {
        const unsigned act0 = (active >> s8) & 1u;
        const unsigned act1 = (active >> (s8 + 8)) & 1u;
        float av = act0 ? fabsf(a0[k]) : -1.f;
        int idx = s8;
        {
            float av1 = act1 ? fabsf(a1[k]) : -1.f;
            if (av1 > av) { av = av1; idx = s8 + 8; }
        }
        #pragma unroll
        for (int d = 1; d < 8; d <<= 1) {
            float ov = __shfl_xor(av, d, 8);
            int   oi = __shfl_xor(idx, d, 8);
            if (ov > av || (ov == av && oi < idx)) { av = ov; idx = oi; }
        }
        const int p = idx;
        const int plane = p & 7;
        const bool phi = (p & 8) != 0;
        float psel = phi ? a1[k] : a0[k];
        const float pk = __shfl(psel, plane, 8);
        const float rcp = 1.0f / pk;

        if (s8 == p)     myd0 = pk;
        if (s8 + 8 == p) myd1 = pk;
        inv += __popc(active & ((1u << p) - 1u));
        active &= ~(1u << p);

        const float f0 = (act0 && s8 != p)       ? a0[k] * rcp : 0.f;
        const float f1 = (act1 && (s8 + 8) != p) ? a1[k] * rcp : 0.f;

        #pragma unroll
        for (int j = k + 1; j < 16; j++) {
            float sel = phi ? a1[j] : a0[j];
            float pv = __shfl(sel, plane, 8);
            a0[j] = fmaf(-f0, pv, a0[j]);
            a1[j] = fmaf(-f1, pv, a1[j]);
        }
    }

    float ld = logf(fabsf(myd0)) + logf(fabsf(myd1));
    int ng = ((myd0 < 0.f) ? 1 : 0) + ((myd1 < 0.f) ? 1 : 0);
    #pragma unroll
    for (int d = 1; d < 8; d <<= 1) {
        ld += __shfl_xor(ld, d, 8);
        ng += __shfl_xor(ng, d, 8);
    }
    const int neg = (ng + inv) & 1;

    const float ld_o  = __shfl_xor(ld, 8, 16);
    const int   neg_o = __shfl_xor(neg, 8, 16);

    if ((lane & 15) == 0 && valid) {
        out[batch]     = ld + ld_o;                                      // re plane
        out[B + batch] = 3.14159265358979323846f * (float)(neg + neg_o); // im plane
    }
}

extern "C" void kernel_launch(void* const* d_in, const int* in_sizes, int n_in,
                              void* d_out, int out_size, void* d_ws, size_t ws_size,
                              hipStream_t stream) {
    const int* nocc = (const int*)d_in[0];
    const float* W  = (const float*)d_in[1];
    float* out = (float*)d_out;
    const int B = in_sizes[0] / 128;                 // 65536
    const int blocks = (B + NB - 1) / NB;            // 2048
    backflow_kernel<<<blocks, 512, 0, stream>>>(nocc, W, out, B);
}